// Round 14
// baseline (360.718 us; speedup 1.0000x reference)
//
#include <hip/hip_runtime.h>

typedef unsigned short u16;
typedef short short8 __attribute__((ext_vector_type(8)));
typedef float f32x4 __attribute__((ext_vector_type(4)));
typedef unsigned short u16x4 __attribute__((ext_vector_type(4)));

typedef short8 short8_a __attribute__((may_alias));
typedef f32x4 f32x4_a __attribute__((may_alias));
typedef u16x4 u16x4_a __attribute__((may_alias));
typedef unsigned int uint_a __attribute__((may_alias));

__device__ __forceinline__ u16 f2b(float f) {
  unsigned u = __float_as_uint(f);
  u += 0x7FFFu + ((u >> 16) & 1u);
  return (u16)(u >> 16);
}

// Nop-free MFMA: safe when D is next read >16cy away or behind a guard below.
__device__ __forceinline__ void mfma_b(f32x4& d, short8 a, short8 b) {
  asm("v_mfma_f32_16x16x32_bf16 %0, %1, %2, %0" : "+v"(d) : "v"(a), "v"(b));
}

// MFMA->VALU hazard guards, register-tied (dataflow-ordered; rule #18 safe).
__device__ __forceinline__ void guard4(f32x4& a, f32x4& b, f32x4& c, f32x4& d) {
  asm volatile("s_nop 7\n\ts_nop 7" : "+v"(a), "+v"(b), "+v"(c), "+v"(d));
}
__device__ __forceinline__ void guard8(f32x4* o) {
  asm volatile("s_nop 7\n\ts_nop 7"
               : "+v"(o[0]), "+v"(o[1]), "+v"(o[2]), "+v"(o[3]),
                 "+v"(o[4]), "+v"(o[5]), "+v"(o[6]), "+v"(o[7]));
}

__device__ __forceinline__ void gload16(const void* g, void* l) {
  __builtin_amdgcn_global_load_lds((__attribute__((address_space(1))) void*)(g),
                                   (__attribute__((address_space(3))) void*)(l),
                                   16, 0, 0);
}

__device__ __forceinline__ void bar_v0() {
  asm volatile("s_waitcnt vmcnt(0)\n\ts_barrier" ::: "memory");
}
__device__ __forceinline__ void bar_v3() {
  asm volatile("s_waitcnt vmcnt(3)\n\ts_barrier" ::: "memory");
}
__device__ __forceinline__ void bar_v4() {
  asm volatile("s_waitcnt vmcnt(4)\n\ts_barrier" ::: "memory");
}
__device__ __forceinline__ void bar_v8() {
  asm volatile("s_waitcnt vmcnt(8)\n\ts_barrier" ::: "memory");
}

// ---------------- merged prep: all fp32->bf16 casts + rope table (verified) ----
__global__ __launch_bounds__(256)
void k_prep(const float* __restrict__ x, const float* __restrict__ wq,
            const float* __restrict__ wk, const float* __restrict__ wv,
            const float* __restrict__ wo, u16* __restrict__ xb,
            u16* __restrict__ wB, u16* __restrict__ wob,
            float* __restrict__ cost, float* __restrict__ sint) {
  const long i = (long)blockIdx.x * 256 + threadIdx.x;
  const float* src;
  u16* dst;
  long j;
  if (i < 6291456) {
    if (i < 2097152) { src = x; dst = xb; j = i; }
    else { src = wq; dst = wB; j = i - 2097152; }
  } else if (i < 8388608) {
    if (i < 7340032) { src = wk; dst = wB + 16777216; j = i - 6291456; }
    else { src = wv; dst = wB + 20971520; j = i - 7340032; }
  } else if (i < 12582912) {
    src = wo; dst = wob; j = i - 8388608;
  } else {
    long ti = i - 12582912;  // [0, 131072): rope table
    int s = (int)(ti >> 6), jj = (int)(ti & 63);
    float freq = powf(500000.0f, -(float)jj * (1.0f / 64.0f));
    float a = (float)s * freq;
    float sv, cv;
    sincosf(a, &sv, &cv);
    cost[ti] = cv;
    sint[ti] = sv;
    return;
  }
  f32x4 v = ((const f32x4_a*)src)[j];
  u16x4 o;
  o[0] = f2b(v[0]); o[1] = f2b(v[1]); o[2] = f2b(v[2]); o[3] = f2b(v[3]);
  ((u16x4_a*)dst)[j] = o;
}

// ===== QKV GEMM: 256^2 tile, BK=32, 4-buf counted-vmcnt pipeline (t2-derived) =====
// C[2048][6144] = xb * wB^T. 8 waves (2Mx4N), per-wave 128x64 output.
// Swizzle involution keyed on (row>>1)&3 both sides (t2-verified):
//   write: LDS[row][s] = G[row][s ^ ((row>>1)&3)], row=sub*128+(tid>>2)
//   read : slot = hi ^ ((lo>>1)&3)
// Pipeline: stage t+3 each iter; bar vmcnt(8) keeps 2 tiles in flight (T4).
// Epilogue: RoPE*scale->Qb / RoPE->Kb / transpose->Vt (k_gemm8-verified).
#define QK_SCALE 0.08838834764831845f
__global__ __launch_bounds__(512, 1)
void k_gemmX(const u16* __restrict__ A, const u16* __restrict__ B,
             const float* __restrict__ cost, const float* __restrict__ sint,
             u16* __restrict__ Qb, u16* __restrict__ Kb, u16* __restrict__ Vt) {
  extern __shared__ u16 ldsx[];
  u16* As = ldsx;            // 4 bufs x 8192 elems (256 rows x 32 k)
  u16* Bs = ldsx + 32768;    // 4 bufs x 8192 elems
  const int K = 4096;
  const int tid = threadIdx.x;
  const int w = tid >> 6, lane = tid & 63;
  const int hi = lane >> 4, lo = lane & 15;
  const int wr = w >> 2, wc = w & 3;  // 2M x 4N waves
  int bid = blockIdx.x;               // 192 = 8(tm) x 24(tn)
  bid = (bid & 7) * 24 + (bid >> 3);  // XCD swizzle (192%8==0)
  const int tm = bid / 24, tn = bid - (bid / 24) * 24;
  const int m0 = tm << 8, n0 = tn << 8;

  const int r2 = tid >> 2;  // 0..127
  const int ks = (((tid & 3) ^ ((tid >> 3) & 3)) << 3);  // source slot (elems)
  const u16* Ag0 = A + (long)(m0 + r2) * K + ks;
  const u16* Ag1 = A + (long)(m0 + 128 + r2) * K + ks;
  const u16* Bg0 = B + (long)(n0 + r2) * K + ks;
  const u16* Bg1 = B + (long)(n0 + 128 + r2) * K + ks;
  const int sb = w * 512;  // wave-uniform dest base (elems); sub1 at +4096

  f32x4 acc[8][4] = {};
  const int hs = hi ^ ((lo >> 1) & 3);  // swizzled read slot
  const int sA0 = (wr * 128 + lo) * 32 + hs * 8;  // + fm*512
  const int sB0 = (wc * 64 + lo) * 32 + hs * 8;   // + fn*512

  const int nt = K >> 5;  // 128 K-tiles

#define STGX(kt, bi)                                          \
  {                                                           \
    gload16(Ag0 + (kt)*32, As + (bi)*8192 + sb);              \
    gload16(Ag1 + (kt)*32, As + (bi)*8192 + 4096 + sb);       \
    gload16(Bg0 + (kt)*32, Bs + (bi)*8192 + sb);              \
    gload16(Bg1 + (kt)*32, Bs + (bi)*8192 + 4096 + sb);       \
  }

  // prologue: stage tiles 0,1,2; wait tile 0 (8 newer loads in flight)
  STGX(0, 0); STGX(1, 1); STGX(2, 2);
  bar_v8();

  for (int t = 0; t < nt; ++t) {
    const int cb = t & 3;
    if (t + 3 < nt) STGX(t + 3, (t + 3) & 3);
    const u16* Ab_ = As + cb * 8192;
    const u16* Bb_ = Bs + cb * 8192;
    short8 afr[8], bfr[4];
#pragma unroll
    for (int fn = 0; fn < 4; ++fn)
      bfr[fn] = *(const short8_a*)(Bb_ + sB0 + fn * 512);
#pragma unroll
    for (int fm = 0; fm < 8; ++fm)
      afr[fm] = *(const short8_a*)(Ab_ + sA0 + fm * 512);
    __builtin_amdgcn_s_setprio(1);
#pragma unroll
    for (int fm = 0; fm < 8; ++fm)
#pragma unroll
      for (int fn = 0; fn < 4; ++fn) mfma_b(acc[fm][fn], afr[fm], bfr[fn]);
    __builtin_amdgcn_s_setprio(0);
    if (t + 3 < nt) bar_v8();       // tile t+1 landed; t+2,t+3 in flight
    else if (t + 2 < nt) bar_v4();  // tail: t+2 in flight
    else bar_v0();                  // drain
  }
#undef STGX

  guard8(&acc[0][0]); guard8(&acc[2][0]); guard8(&acc[4][0]); guard8(&acc[6][0]);

  if (n0 < 5120) {  // Q or K: RoPE (pair partner in lane lo^1)
    const bool isQ = (n0 < 4096);
#pragma unroll
    for (int fm = 0; fm < 8; ++fm) {
      const int row0 = m0 + wr * 128 + fm * 16 + hi * 4;
#pragma unroll
      for (int fn = 0; fn < 4; ++fn) {
        const int c = n0 + wc * 64 + fn * 16 + lo;
        const int j0 = (c & 127) >> 1;
        const bool even = ((c & 1) == 0);
#pragma unroll
        for (int r = 0; r < 4; ++r) {
          float own = acc[fm][fn][r];
          float part = __shfl_xor(own, 1);
          const int s_ = row0 + r;
          const float cv = cost[s_ * 64 + j0];
          const float sv = sint[s_ * 64 + j0];
          float res = even ? (own * cv - part * sv) : (part * sv + own * cv);
          if (isQ)
            Qb[(long)s_ * 4096 + c] = f2b(res * QK_SCALE);
          else
            Kb[(long)s_ * 1024 + (c - 4096)] = f2b(res);
        }
      }
    }
  } else {  // V: transposed store Vt[c][s], 4 rows packed
#pragma unroll
    for (int fm = 0; fm < 8; ++fm) {
      const int row0 = m0 + wr * 128 + fm * 16 + hi * 4;
#pragma unroll
      for (int fn = 0; fn < 4; ++fn) {
        const int vc = n0 - 5120 + wc * 64 + fn * 16 + lo;
        u16x4 pk;
#pragma unroll
        for (int r = 0; r < 4; ++r) pk[r] = f2b(acc[fm][fn][r]);
        *(u16x4_a*)(Vt + (long)vc * 2048 + row0) = pk;
      }
    }
  }
}

// ---- 128x256-tile 8-wave out-projection (verified R11) ----
__global__ __launch_bounds__(512, 2)
void k_gemm_t2(const u16* __restrict__ A, const u16* __restrict__ B,
               float* __restrict__ C) {
  extern __shared__ u16 lds2[];
  u16* As = lds2;           // 3 bufs x 4096 elems (128 x 32)
  u16* Bs = lds2 + 12288;   // 3 bufs x 8192 elems (256 x 32)
  const int K = 4096, N = 4096;
  const int tid = threadIdx.x;
  const int w = tid >> 6, lane = tid & 63;
  const int hi = lane >> 4, lo = lane & 15;
  const int wr = w >> 2, wc = w & 3;
  int bid = blockIdx.x;               // 256 = 16(tm) x 16(tn)
  bid = (bid & 7) * 32 + (bid >> 3);  // XCD swizzle
  const int tm = bid >> 4, tn = bid & 15;
  const int m0 = tm << 7, n0 = tn << 8;

  const int r2 = tid >> 2;
  const int ks = (((tid & 3) ^ ((tid >> 3) & 3)) << 3);
  const u16* Ag = A + (long)(m0 + r2) * K + ks;
  const u16* Bg0 = B + (long)(n0 + r2) * K + ks;
  const u16* Bg1 = B + (long)(n0 + 128 + r2) * K + ks;
  const int sb = w * 512;

  f32x4 acc[4][4] = {};
  const int hs = hi ^ ((lo >> 1) & 3);
  const int aoff = (wr * 64 + lo) * 32 + hs * 8;
  const int boff = (wc * 64 + lo) * 32 + hs * 8;

  const int nt = K >> 5;
  int i0 = 0, i1 = 1, i2 = 2;

#define STG2(kt, bi)                                      \
  {                                                       \
    gload16(Ag + (kt)*32, As + (bi)*4096 + sb);           \
    gload16(Bg0 + (kt)*32, Bs + (bi)*8192 + sb);          \
    gload16(Bg1 + (kt)*32, Bs + (bi)*8192 + 4096 + sb);   \
  }

  STG2(0, 0);
  STG2(1, 1);
  bar_v3();

  for (int t = 0; t < nt; ++t) {
    if (t + 2 < nt) STG2(t + 2, i2);
    short8 af[4], bf[4];
#pragma unroll
    for (int m = 0; m < 4; ++m)
      af[m] = *(const short8_a*)(As + i0 * 4096 + aoff + m * 512);
#pragma unroll
    for (int n = 0; n < 4; ++n)
      bf[n] = *(const short8_a*)(Bs + i0 * 8192 + boff + n * 512);
    __builtin_amdgcn_s_setprio(1);
#pragma unroll
    for (int m = 0; m < 4; ++m)
#pragma unroll
      for (int n = 0; n < 4; ++n) mfma_b(acc[m][n], af[m], bf[n]);
    __builtin_amdgcn_s_setprio(0);
    if (t + 2 < nt) bar_v3();
    else bar_v0();
    const int tmp = i0; i0 = i1; i1 = i2; i2 = tmp;
  }
#undef STG2
  guard8(&acc[0][0]);
  guard8(&acc[2][0]);

#pragma unroll
  for (int m = 0; m < 4; ++m) {
    const int row0 = m0 + wr * 64 + m * 16 + hi * 4;
#pragma unroll
    for (int n = 0; n < 4; ++n) {
      const int col = n0 + wc * 64 + n * 16 + lo;
#pragma unroll
      for (int r = 0; r < 4; ++r)
        C[(long)(row0 + r) * N + col] = acc[m][n][r];
    }
  }
}

// ---------------- causal GQA flash attention (verified) ----------------
#define KLD 136
#define VLD 72
__global__ __launch_bounds__(256, 2)
void k_attn(const u16* __restrict__ Qb, const u16* __restrict__ Kb,
            const u16* __restrict__ Vt, u16* __restrict__ Ab) {
  __shared__ u16 Ks[64 * KLD];
  __shared__ u16 Vs[128 * VLD];
  __shared__ u16 Ps[4 * 16 * VLD];

  const int tid = threadIdx.x;
  const int w = tid >> 6, lane = tid & 63;
  const int hi = lane >> 4, lo = lane & 15;
  const int qt = 31 - (blockIdx.x >> 5);
  const int h = blockIdx.x & 31;
  const int hkv = h >> 2;
  const int q0 = qt * 64;
  const int qrow = q0 + w * 16 + lo;

  short8 qf[4];
#pragma unroll
  for (int c = 0; c < 4; ++c)
    qf[c] = *(const short8_a*)(Qb + (long)qrow * 4096 + h * 128 + c * 32 + hi * 8);

  f32x4 o[8] = {};
  float m_run = -1e30f, l_run = 0.f;
  u16* Pw = Ps + w * (16 * VLD);

  const int ntiles = qt + 1;
  for (int t = 0; t < ntiles; ++t) {
    const int kv0 = t * 64;
    __syncthreads();
#pragma unroll
    for (int r = 0; r < 4; ++r) {
      int i = r * 256 + tid;
      int key = i >> 4, d8 = (i & 15) * 8;
      short8 v = *(const short8_a*)(Kb + (long)(kv0 + key) * 1024 + hkv * 128 + d8);
      *(short8_a*)(Ks + key * KLD + d8) = v;
    }
#pragma unroll
    for (int r = 0; r < 4; ++r) {
      int i = r * 256 + tid;
      int dd = i >> 3, k8 = (i & 7) * 8;
      short8 v = *(const short8_a*)(Vt + (long)hkv * 262144 + (long)dd * 2048 + kv0 + k8);
      *(short8_a*)(Vs + dd * VLD + k8) = v;
    }
    __syncthreads();

    f32x4 sc[4] = {};
#pragma unroll
    for (int c = 0; c < 4; ++c) {
#pragma unroll
      for (int kt = 0; kt < 4; ++kt) {
        short8 kf = *(const short8_a*)(Ks + (kt * 16 + lo) * KLD + c * 32 + hi * 8);
        mfma_b(sc[kt], kf, qf[c]);
      }
    }
    guard4(sc[0], sc[1], sc[2], sc[3]);

    if (t == ntiles - 1) {
#pragma unroll
      for (int kt = 0; kt < 4; ++kt)
#pragma unroll
        for (int r = 0; r < 4; ++r) {
          int key = kv0 + kt * 16 + hi * 4 + r;
          if (key > qrow) sc[kt][r] = -1e30f;
        }
    }
    float tmax = -1e30f;
#pragma unroll
    for (int kt = 0; kt < 4; ++kt)
#pragma unroll
      for (int r = 0; r < 4; ++r) tmax = fmaxf(tmax, sc[kt][r]);
    tmax = fmaxf(tmax, __shfl_xor(tmax, 16));
    tmax = fmaxf(tmax, __shfl_xor(tmax, 32));
    float m_new = fmaxf(m_run, tmax);
    float scale = __expf(m_run - m_new);
    float psum = 0.f;
    float p[16];
#pragma unroll
    for (int kt = 0; kt < 4; ++kt)
#pragma unroll
      for (int r = 0; r < 4; ++r) {
        float pv = __expf(sc[kt][r] - m_new);
        p[kt * 4 + r] = pv;
        psum += pv;
      }
    psum += __shfl_xor(psum, 16);
    psum += __shfl_xor(psum, 32);
    l_run = l_run * scale + psum;
    m_run = m_new;
    float srow[4];
#pragma unroll
    for (int r = 0; r < 4; ++r) srow[r] = __shfl(scale, hi * 4 + r);
#pragma unroll
    for (int n = 0; n < 8; ++n)
#pragma unroll
      for (int r = 0; r < 4; ++r) o[n][r] *= srow[r];
#pragma unroll
    for (int kt = 0; kt < 4; ++kt) {
      unsigned p01 = (unsigned)f2b(p[kt * 4]) | ((unsigned)f2b(p[kt * 4 + 1]) << 16);
      unsigned p23 = (unsigned)f2b(p[kt * 4 + 2]) | ((unsigned)f2b(p[kt * 4 + 3]) << 16);
      *(uint_a*)(Pw + lo * VLD + kt * 16 + hi * 4) = p01;
      *(uint_a*)(Pw + lo * VLD + kt * 16 + hi * 4 + 2) = p23;
    }
    __syncthreads();
#pragma unroll
    for (int c = 0; c < 2; ++c) {
      short8 pf = *(const short8_a*)(Pw + lo * VLD + c * 32 + hi * 8);
#pragma unroll
      for (int n = 0; n < 8; ++n) {
        short8 vf = *(const short8_a*)(Vs + (n * 16 + lo) * VLD + c * 32 + hi * 8);
        mfma_b(o[n], pf, vf);
      }
    }
  }
  guard8(o);

  float inv = 1.0f / l_run;
  float irow[4];
#pragma unroll
  for (int r = 0; r < 4; ++r) irow[r] = __shfl(inv, hi * 4 + r);
#pragma unroll
  for (int n = 0; n < 8; ++n)
#pragma unroll
    for (int r = 0; r < 4; ++r) {
      int q = q0 + w * 16 + hi * 4 + r;
      Ab[(long)q * 4096 + h * 128 + n * 16 + lo] = f2b(o[n][r] * irow[r]);
    }
}

// ---------------- host ----------------
extern "C" void kernel_launch(void* const* d_in, const int* in_sizes, int n_in,
                              void* d_out, int out_size, void* d_ws, size_t ws_size,
                              hipStream_t stream) {
  const float* x = (const float*)d_in[0];
  const float* wq = (const float*)d_in[1];
  const float* wk = (const float*)d_in[2];
  const float* wv = (const float*)d_in[3];
  const float* wo = (const float*)d_in[4];
  float* out = (float*)d_out;
  char* ws = (char*)d_ws;

  size_t off = 0;
  u16* xb = (u16*)(ws + off); off += 16777216;     // x 2048x4096 bf16
  u16* wB = (u16*)(ws + off); off += 50331648;     // [wq;wk;wv] 6144x4096 bf16
  u16* wob = (u16*)(ws + off); off += 33554432;    // wo bf16
  u16* Qb = (u16*)(ws + off); off += 16777216;     // roped, scaled Q
  u16* Kb = (u16*)(ws + off); off += 4194304;      // roped K
  u16* Vtb = (u16*)(ws + off); off += 4194304;     // transposed V
  float* cost = (float*)(ws + off); off += 524288; // 2048x64
  float* sint = (float*)(ws + off); off += 524288;
  u16* Ab = (u16*)(ws + off); off += 16777216;     // attn out

  static bool attr_set = false;
  if (!attr_set) {
    hipFuncSetAttribute((const void*)k_gemmX,
                        hipFuncAttributeMaxDynamicSharedMemorySize, 131072);
    hipFuncSetAttribute((const void*)k_gemm_t2,
                        hipFuncAttributeMaxDynamicSharedMemorySize, 73728);
    attr_set = true;
  }

  // prep: all weight/x casts + rope table
  k_prep<<<49664, 256, 0, stream>>>(x, wq, wk, wv, wo, xb, wB, wob, cost, sint);

  // fused QKV projection: 256^2 tile, 4-buf counted-vmcnt pipeline
  k_gemmX<<<192, 512, 131072, stream>>>(xb, wB, cost, sint, Qb, Kb, Vtb);

  // attention (verified)
  k_attn<<<1024, 256, 0, stream>>>(Qb, Kb, Vtb, Ab);

  // output projection (verified R11)
  k_gemm_t2<<<256, 512, 73728, stream>>>(Ab, wob, out);
}

// Round 16
// 350.019 us; speedup vs baseline: 1.0306x; 1.0306x over previous
//
#include <hip/hip_runtime.h>

typedef unsigned short u16;
typedef short short8 __attribute__((ext_vector_type(8)));
typedef float f32x4 __attribute__((ext_vector_type(4)));
typedef unsigned short u16x4 __attribute__((ext_vector_type(4)));

typedef short8 short8_a __attribute__((may_alias));
typedef f32x4 f32x4_a __attribute__((may_alias));
typedef u16x4 u16x4_a __attribute__((may_alias));
typedef unsigned int uint_a __attribute__((may_alias));

__device__ __forceinline__ u16 f2b(float f) {
  unsigned u = __float_as_uint(f);
  u += 0x7FFFu + ((u >> 16) & 1u);
  return (u16)(u >> 16);
}

// Nop-free MFMA: safe when D is next read >16cy away or behind a guard below.
__device__ __forceinline__ void mfma_b(f32x4& d, short8 a, short8 b) {
  asm("v_mfma_f32_16x16x32_bf16 %0, %1, %2, %0" : "+v"(d) : "v"(a), "v"(b));
}

// MFMA->VALU hazard guards, register-tied (dataflow-ordered; rule #18 safe).
__device__ __forceinline__ void guard4(f32x4& a, f32x4& b, f32x4& c, f32x4& d) {
  asm volatile("s_nop 7\n\ts_nop 7" : "+v"(a), "+v"(b), "+v"(c), "+v"(d));
}
__device__ __forceinline__ void guard8(f32x4* o) {
  asm volatile("s_nop 7\n\ts_nop 7"
               : "+v"(o[0]), "+v"(o[1]), "+v"(o[2]), "+v"(o[3]),
                 "+v"(o[4]), "+v"(o[5]), "+v"(o[6]), "+v"(o[7]));
}

__device__ __forceinline__ void gload16(const void* g, void* l) {
  __builtin_amdgcn_global_load_lds((__attribute__((address_space(1))) void*)(g),
                                   (__attribute__((address_space(3))) void*)(l),
                                   16, 0, 0);
}

__device__ __forceinline__ void bar_v0() {
  asm volatile("s_waitcnt vmcnt(0)\n\ts_barrier" ::: "memory");
}
__device__ __forceinline__ void bar_v3() {
  asm volatile("s_waitcnt vmcnt(3)\n\ts_barrier" ::: "memory");
}

// ---------------- merged prep: all fp32->bf16 casts + rope table (verified) ----
__global__ __launch_bounds__(256)
void k_prep(const float* __restrict__ x, const float* __restrict__ wq,
            const float* __restrict__ wk, const float* __restrict__ wv,
            const float* __restrict__ wo, u16* __restrict__ xb,
            u16* __restrict__ wB, u16* __restrict__ wob,
            float* __restrict__ cost, float* __restrict__ sint) {
  const long i = (long)blockIdx.x * 256 + threadIdx.x;
  const float* src;
  u16* dst;
  long j;
  if (i < 6291456) {
    if (i < 2097152) { src = x; dst = xb; j = i; }
    else { src = wq; dst = wB; j = i - 2097152; }
  } else if (i < 8388608) {
    if (i < 7340032) { src = wk; dst = wB + 16777216; j = i - 6291456; }
    else { src = wv; dst = wB + 20971520; j = i - 7340032; }
  } else if (i < 12582912) {
    src = wo; dst = wob; j = i - 8388608;
  } else {
    long ti = i - 12582912;  // [0, 131072): rope table
    int s = (int)(ti >> 6), jj = (int)(ti & 63);
    float freq = powf(500000.0f, -(float)jj * (1.0f / 64.0f));
    float a = (float)s * freq;
    float sv, cv;
    sincosf(a, &sv, &cv);
    cost[ti] = cv;
    sint[ti] = sv;
    return;
  }
  f32x4 v = ((const f32x4_a*)src)[j];
  u16x4 o;
  o[0] = f2b(v[0]); o[1] = f2b(v[1]); o[2] = f2b(v[2]); o[3] = f2b(v[3]);
  ((u16x4_a*)dst)[j] = o;
}

// ================= 256^2 8-wave QKV GEMM (R11-verified, mid-loop B-stage) =========
#define QK_SCALE 0.08838834764831845f
__global__ __launch_bounds__(512, 2)
void k_gemm8(const u16* __restrict__ A, const u16* __restrict__ B,
             const float* __restrict__ cost, const float* __restrict__ sint,
             u16* __restrict__ Qb, u16* __restrict__ Kb, u16* __restrict__ Vt) {
  extern __shared__ u16 lds[];  // A: [2][256][64] @0, B: [2][256][64] @32768
  const int K = 4096;
  const int tid = threadIdx.x;
  const int w = tid >> 6, lane = tid & 63;
  const int hi = lane >> 4, lo = lane & 15;
  const int wr = w >> 2, wc = w & 3;  // 2M x 4N wave grid
  int bid = blockIdx.x;               // 192 = 8 XCD-groups x 24
  bid = (bid & 7) * 24 + (bid >> 3);
  const int tm = bid / 24, tn = bid - (bid / 24) * 24;
  const int m0 = tm << 8, n0 = tn << 8;

  const int kx = (((tid & 7) ^ ((tid >> 3) & 7)) << 3);  // elems
  const int r3 = tid >> 3;                               // 0..63

  f32x4 acc[8][4] = {};
  short8 afr[4][2], bfr[4][2];

  const int sA0 = (wr * 128 + lo) * 64;  // + fm*16*64
  const int sB0 = (wc * 64 + lo) * 64;   // + fn*16*64
  const int sl0 = ((0 * 4 + hi) ^ (lo & 7)) * 8;
  const int sl1 = ((1 * 4 + hi) ^ (lo & 7)) * 8;

#define STAGE_A(sbuf, h, kt)                                                    \
  {                                                                             \
    _Pragma("unroll") for (int l = 0; l < 2; ++l) {                             \
      gload16(A + (long)(m0 + (h)*128 + l * 64 + r3) * K + (kt)*64 + kx,        \
              lds + (sbuf)*16384 + ((h)*128 + l * 64 + w * 8) * 64);            \
    }                                                                           \
  }
#define STAGE_B(sbuf, h, kt)                                                    \
  {                                                                             \
    _Pragma("unroll") for (int l = 0; l < 2; ++l) {                             \
      gload16(B + (long)(n0 + (h)*128 + l * 64 + r3) * K + (kt)*64 + kx,        \
              lds + 32768 + (sbuf)*16384 + ((h)*128 + l * 64 + w * 8) * 64);    \
    }                                                                           \
  }

  // prologue: stage tile 0 -> buf0, drain once
  STAGE_A(0, 0, 0); STAGE_A(0, 1, 0);
  STAGE_B(0, 0, 0); STAGE_B(0, 1, 0);
  bar_v0();

  const int NI = K >> 7;  // 32 iters, 2 K-tiles each
#define HALF_ITER(buf, stile, sbuf, dostage)                                    \
  {                                                                             \
    const u16* Ab_ = lds + (buf)*16384;                                         \
    const u16* Bb_ = lds + 32768 + (buf)*16384;                                 \
    if (dostage) { STAGE_A(sbuf, 0, stile); STAGE_A(sbuf, 1, stile); }          \
    _Pragma("unroll") for (int fn = 0; fn < 4; ++fn) {                          \
      bfr[fn][0] = *(const short8_a*)(Bb_ + sB0 + fn * 1024 + sl0);             \
      bfr[fn][1] = *(const short8_a*)(Bb_ + sB0 + fn * 1024 + sl1);             \
    }                                                                           \
    _Pragma("unroll") for (int fm = 0; fm < 4; ++fm) {                          \
      afr[fm][0] = *(const short8_a*)(Ab_ + sA0 + fm * 1024 + sl0);             \
      afr[fm][1] = *(const short8_a*)(Ab_ + sA0 + fm * 1024 + sl1);             \
    }                                                                           \
    __builtin_amdgcn_s_setprio(1);                                              \
    _Pragma("unroll") for (int fm = 0; fm < 4; ++fm)                            \
      _Pragma("unroll") for (int fn = 0; fn < 4; ++fn) {                        \
        mfma_b(acc[fm][fn], afr[fm][0], bfr[fn][0]);                            \
        mfma_b(acc[fm][fn], afr[fm][1], bfr[fn][1]);                            \
      }                                                                         \
    __builtin_amdgcn_s_setprio(0);                                              \
    if (dostage) { STAGE_B(sbuf, 0, stile); STAGE_B(sbuf, 1, stile); }          \
    _Pragma("unroll") for (int fm = 0; fm < 4; ++fm) {                          \
      afr[fm][0] = *(const short8_a*)(Ab_ + sA0 + (fm + 4) * 1024 + sl0);       \
      afr[fm][1] = *(const short8_a*)(Ab_ + sA0 + (fm + 4) * 1024 + sl1);       \
    }                                                                           \
    __builtin_amdgcn_s_setprio(1);                                              \
    _Pragma("unroll") for (int fm = 0; fm < 4; ++fm)                            \
      _Pragma("unroll") for (int fn = 0; fn < 4; ++fn) {                        \
        mfma_b(acc[fm + 4][fn], afr[fm][0], bfr[fn][0]);                        \
        mfma_b(acc[fm + 4][fn], afr[fm][1], bfr[fn][1]);                        \
      }                                                                         \
    __builtin_amdgcn_s_setprio(0);                                              \
    bar_v0();                                                                   \
  }

  for (int it = 0; it < NI; ++it) {
    HALF_ITER(0, 2 * it + 1, 1, true);
    HALF_ITER(1, 2 * it + 2, 0, (it + 1 < NI));
  }

  guard8(&acc[0][0]); guard8(&acc[2][0]); guard8(&acc[4][0]); guard8(&acc[6][0]);

  if (n0 < 5120) {  // Q or K: RoPE (pair partner in lane lo^1)
    const bool isQ = (n0 < 4096);
#pragma unroll
    for (int fm = 0; fm < 8; ++fm) {
      const int row0 = m0 + wr * 128 + fm * 16 + hi * 4;
#pragma unroll
      for (int fn = 0; fn < 4; ++fn) {
        const int c = n0 + wc * 64 + fn * 16 + lo;
        const int j0 = (c & 127) >> 1;
        const bool even = ((c & 1) == 0);
#pragma unroll
        for (int r = 0; r < 4; ++r) {
          float own = acc[fm][fn][r];
          float part = __shfl_xor(own, 1);
          const int s_ = row0 + r;
          const float cv = cost[s_ * 64 + j0];
          const float sv = sint[s_ * 64 + j0];
          float res = even ? (own * cv - part * sv) : (part * sv + own * cv);
          if (isQ)
            Qb[(long)s_ * 4096 + c] = f2b(res * QK_SCALE);
          else
            Kb[(long)s_ * 1024 + (c - 4096)] = f2b(res);
        }
      }
    }
  } else {  // V: transposed store Vt[c][s], 4 rows packed
#pragma unroll
    for (int fm = 0; fm < 8; ++fm) {
      const int row0 = m0 + wr * 128 + fm * 16 + hi * 4;
#pragma unroll
      for (int fn = 0; fn < 4; ++fn) {
        const int vc = n0 - 5120 + wc * 64 + fn * 16 + lo;
        u16x4 pk;
#pragma unroll
        for (int r = 0; r < 4; ++r) pk[r] = f2b(acc[fm][fn][r]);
        *(u16x4_a*)(Vt + (long)vc * 2048 + row0) = pk;
      }
    }
  }
#undef HALF_ITER
#undef STAGE_A
#undef STAGE_B
}

// ---- 128x256-tile 8-wave out-projection (verified R11) ----
__global__ __launch_bounds__(512, 2)
void k_gemm_t2(const u16* __restrict__ A, const u16* __restrict__ B,
               float* __restrict__ C) {
  extern __shared__ u16 lds2[];
  u16* As = lds2;           // 3 bufs x 4096 elems (128 x 32)
  u16* Bs = lds2 + 12288;   // 3 bufs x 8192 elems (256 x 32)
  const int K = 4096, N = 4096;
  const int tid = threadIdx.x;
  const int w = tid >> 6, lane = tid & 63;
  const int hi = lane >> 4, lo = lane & 15;
  const int wr = w >> 2, wc = w & 3;
  int bid = blockIdx.x;               // 256 = 16(tm) x 16(tn)
  bid = (bid & 7) * 32 + (bid >> 3);  // XCD swizzle
  const int tm = bid >> 4, tn = bid & 15;
  const int m0 = tm << 7, n0 = tn << 8;

  const int r2 = tid >> 2;
  const int ks = (((tid & 3) ^ ((tid >> 3) & 3)) << 3);
  const u16* Ag = A + (long)(m0 + r2) * K + ks;
  const u16* Bg0 = B + (long)(n0 + r2) * K + ks;
  const u16* Bg1 = B + (long)(n0 + 128 + r2) * K + ks;
  const int sb = w * 512;

  f32x4 acc[4][4] = {};
  const int hs = hi ^ ((lo >> 1) & 3);
  const int aoff = (wr * 64 + lo) * 32 + hs * 8;
  const int boff = (wc * 64 + lo) * 32 + hs * 8;

  const int nt = K >> 5;
  int i0 = 0, i1 = 1, i2 = 2;

#define STG2(kt, bi)                                      \
  {                                                       \
    gload16(Ag + (kt)*32, As + (bi)*4096 + sb);           \
    gload16(Bg0 + (kt)*32, Bs + (bi)*8192 + sb);          \
    gload16(Bg1 + (kt)*32, Bs + (bi)*8192 + 4096 + sb);   \
  }

  STG2(0, 0);
  STG2(1, 1);
  bar_v3();

  for (int t = 0; t < nt; ++t) {
    if (t + 2 < nt) STG2(t + 2, i2);
    short8 af[4], bf[4];
#pragma unroll
    for (int m = 0; m < 4; ++m)
      af[m] = *(const short8_a*)(As + i0 * 4096 + aoff + m * 512);
#pragma unroll
    for (int n = 0; n < 4; ++n)
      bf[n] = *(const short8_a*)(Bs + i0 * 8192 + boff + n * 512);
    __builtin_amdgcn_s_setprio(1);
#pragma unroll
    for (int m = 0; m < 4; ++m)
#pragma unroll
      for (int n = 0; n < 4; ++n) mfma_b(acc[m][n], af[m], bf[n]);
    __builtin_amdgcn_s_setprio(0);
    if (t + 2 < nt) bar_v3();
    else bar_v0();
    const int tmp = i0; i0 = i1; i1 = i2; i2 = tmp;
  }
#undef STG2
  guard8(&acc[0][0]);
  guard8(&acc[2][0]);

#pragma unroll
  for (int m = 0; m < 4; ++m) {
    const int row0 = m0 + wr * 64 + m * 16 + hi * 4;
#pragma unroll
    for (int n = 0; n < 4; ++n) {
      const int col = n0 + wc * 64 + n * 16 + lo;
#pragma unroll
      for (int r = 0; r < 4; ++r)
        C[(long)(row0 + r) * N + col] = acc[m][n][r];
    }
  }
}

// ---------------- causal GQA flash attention (R13-verified, staged V) ----------------
#define KLD 136
#define VLD 72
__global__ __launch_bounds__(256, 2)
void k_attn(const u16* __restrict__ Qb, const u16* __restrict__ Kb,
            const u16* __restrict__ Vt, u16* __restrict__ Ab) {
  __shared__ u16 Ks[64 * KLD];
  __shared__ u16 Vs[128 * VLD];
  __shared__ u16 Ps[4 * 16 * VLD];

  const int tid = threadIdx.x;
  const int w = tid >> 6, lane = tid & 63;
  const int hi = lane >> 4, lo = lane & 15;
  const int qt = 31 - (blockIdx.x >> 5);
  const int h = blockIdx.x & 31;
  const int hkv = h >> 2;
  const int q0 = qt * 64;
  const int qrow = q0 + w * 16 + lo;

  short8 qf[4];
#pragma unroll
  for (int c = 0; c < 4; ++c)
    qf[c] = *(const short8_a*)(Qb + (long)qrow * 4096 + h * 128 + c * 32 + hi * 8);

  f32x4 o[8] = {};
  float m_run = -1e30f, l_run = 0.f;
  u16* Pw = Ps + w * (16 * VLD);

  const int ntiles = qt + 1;
  for (int t = 0; t < ntiles; ++t) {
    const int kv0 = t * 64;
    __syncthreads();
#pragma unroll
    for (int r = 0; r < 4; ++r) {
      int i = r * 256 + tid;
      int key = i >> 4, d8 = (i & 15) * 8;
      short8 v = *(const short8_a*)(Kb + (long)(kv0 + key) * 1024 + hkv * 128 + d8);
      *(short8_a*)(Ks + key * KLD + d8) = v;
    }
#pragma unroll
    for (int r = 0; r < 4; ++r) {
      int i = r * 256 + tid;
      int dd = i >> 3, k8 = (i & 7) * 8;
      short8 v = *(const short8_a*)(Vt + (long)hkv * 262144 + (long)dd * 2048 + kv0 + k8);
      *(short8_a*)(Vs + dd * VLD + k8) = v;
    }
    __syncthreads();

    f32x4 sc[4] = {};
#pragma unroll
    for (int c = 0; c < 4; ++c) {
#pragma unroll
      for (int kt = 0; kt < 4; ++kt) {
        short8 kf = *(const short8_a*)(Ks + (kt * 16 + lo) * KLD + c * 32 + hi * 8);
        mfma_b(sc[kt], kf, qf[c]);
      }
    }
    guard4(sc[0], sc[1], sc[2], sc[3]);

    if (t == ntiles - 1) {
#pragma unroll
      for (int kt = 0; kt < 4; ++kt)
#pragma unroll
        for (int r = 0; r < 4; ++r) {
          int key = kv0 + kt * 16 + hi * 4 + r;
          if (key > qrow) sc[kt][r] = -1e30f;
        }
    }
    float tmax = -1e30f;
#pragma unroll
    for (int kt = 0; kt < 4; ++kt)
#pragma unroll
      for (int r = 0; r < 4; ++r) tmax = fmaxf(tmax, sc[kt][r]);
    tmax = fmaxf(tmax, __shfl_xor(tmax, 16));
    tmax = fmaxf(tmax, __shfl_xor(tmax, 32));
    float m_new = fmaxf(m_run, tmax);
    float scale = __expf(m_run - m_new);
    float psum = 0.f;
    float p[16];
#pragma unroll
    for (int kt = 0; kt < 4; ++kt)
#pragma unroll
      for (int r = 0; r < 4; ++r) {
        float pv = __expf(sc[kt][r] - m_new);
        p[kt * 4 + r] = pv;
        psum += pv;
      }
    psum += __shfl_xor(psum, 16);
    psum += __shfl_xor(psum, 32);
    l_run = l_run * scale + psum;
    m_run = m_new;
    float srow[4];
#pragma unroll
    for (int r = 0; r < 4; ++r) srow[r] = __shfl(scale, hi * 4 + r);
#pragma unroll
    for (int n = 0; n < 8; ++n)
#pragma unroll
      for (int r = 0; r < 4; ++r) o[n][r] *= srow[r];
#pragma unroll
    for (int kt = 0; kt < 4; ++kt) {
      unsigned p01 = (unsigned)f2b(p[kt * 4]) | ((unsigned)f2b(p[kt * 4 + 1]) << 16);
      unsigned p23 = (unsigned)f2b(p[kt * 4 + 2]) | ((unsigned)f2b(p[kt * 4 + 3]) << 16);
      *(uint_a*)(Pw + lo * VLD + kt * 16 + hi * 4) = p01;
      *(uint_a*)(Pw + lo * VLD + kt * 16 + hi * 4 + 2) = p23;
    }
    __syncthreads();
#pragma unroll
    for (int c = 0; c < 2; ++c) {
      short8 pf = *(const short8_a*)(Pw + lo * VLD + c * 32 + hi * 8);
#pragma unroll
      for (int n = 0; n < 8; ++n) {
        short8 vf = *(const short8_a*)(Vs + (n * 16 + lo) * VLD + c * 32 + hi * 8);
        mfma_b(o[n], pf, vf);
      }
    }
  }
  guard8(o);

  float inv = 1.0f / l_run;
  float irow[4];
#pragma unroll
  for (int r = 0; r < 4; ++r) irow[r] = __shfl(inv, hi * 4 + r);
#pragma unroll
  for (int n = 0; n < 8; ++n)
#pragma unroll
    for (int r = 0; r < 4; ++r) {
      int q = q0 + w * 16 + hi * 4 + r;
      Ab[(long)q * 4096 + h * 128 + n * 16 + lo] = f2b(o[n][r] * irow[r]);
    }
}

// ---------------- host ----------------
extern "C" void kernel_launch(void* const* d_in, const int* in_sizes, int n_in,
                              void* d_out, int out_size, void* d_ws, size_t ws_size,
                              hipStream_t stream) {
  const float* x = (const float*)d_in[0];
  const float* wq = (const float*)d_in[1];
  const float* wk = (const float*)d_in[2];
  const float* wv = (const float*)d_in[3];
  const float* wo = (const float*)d_in[4];
  float* out = (float*)d_out;
  char* ws = (char*)d_ws;

  size_t off = 0;
  u16* xb = (u16*)(ws + off); off += 16777216;     // x 2048x4096 bf16
  u16* wB = (u16*)(ws + off); off += 50331648;     // [wq;wk;wv] 6144x4096 bf16
  u16* wob = (u16*)(ws + off); off += 33554432;    // wo bf16
  u16* Qb = (u16*)(ws + off); off += 16777216;     // roped, scaled Q
  u16* Kb = (u16*)(ws + off); off += 4194304;      // roped K
  u16* Vtb = (u16*)(ws + off); off += 4194304;     // transposed V
  float* cost = (float*)(ws + off); off += 524288; // 2048x64
  float* sint = (float*)(ws + off); off += 524288;
  u16* Ab = (u16*)(ws + off); off += 16777216;     // attn out

  static bool attr_set = false;
  if (!attr_set) {
    hipFuncSetAttribute((const void*)k_gemm8,
                        hipFuncAttributeMaxDynamicSharedMemorySize, 131072);
    hipFuncSetAttribute((const void*)k_gemm_t2,
                        hipFuncAttributeMaxDynamicSharedMemorySize, 73728);
    attr_set = true;
  }

  // prep: all weight/x casts + rope table
  k_prep<<<49664, 256, 0, stream>>>(x, wq, wk, wv, wo, xb, wB, wob, cost, sint);

  // fused QKV projection (R11-verified k_gemm8, mid-loop B-stage)
  k_gemm8<<<192, 512, 131072, stream>>>(xb, wB, cost, sint, Qb, Kb, Vtb);

  // attention (R13-verified, staged V)
  k_attn<<<1024, 256, 0, stream>>>(Qb, Kb, Vtb, Ab);

  // output projection (verified R11)
  k_gemm_t2<<<256, 512, 73728, stream>>>(Ab, wob, out);
}

// Round 17
// 316.251 us; speedup vs baseline: 1.1406x; 1.1068x over previous
//
#include <hip/hip_runtime.h>

typedef unsigned short u16;
typedef short short8 __attribute__((ext_vector_type(8)));
typedef float f32x4 __attribute__((ext_vector_type(4)));
typedef unsigned short u16x4 __attribute__((ext_vector_type(4)));

typedef short8 short8_a __attribute__((may_alias));
typedef f32x4 f32x4_a __attribute__((may_alias));
typedef u16x4 u16x4_a __attribute__((may_alias));
typedef unsigned int uint_a __attribute__((may_alias));

__device__ __forceinline__ u16 f2b(float f) {
  unsigned u = __float_as_uint(f);
  u += 0x7FFFu + ((u >> 16) & 1u);
  return (u16)(u >> 16);
}

// Nop-free MFMA: safe when D is next read >16cy away or behind a guard below.
__device__ __forceinline__ void mfma_b(f32x4& d, short8 a, short8 b) {
  asm("v_mfma_f32_16x16x32_bf16 %0, %1, %2, %0" : "+v"(d) : "v"(a), "v"(b));
}

// MFMA->VALU hazard guards, register-tied (dataflow-ordered; rule #18 safe).
__device__ __forceinline__ void guard4(f32x4& a, f32x4& b, f32x4& c, f32x4& d) {
  asm volatile("s_nop 7\n\ts_nop 7" : "+v"(a), "+v"(b), "+v"(c), "+v"(d));
}
__device__ __forceinline__ void guard8(f32x4* o) {
  asm volatile("s_nop 7\n\ts_nop 7"
               : "+v"(o[0]), "+v"(o[1]), "+v"(o[2]), "+v"(o[3]),
                 "+v"(o[4]), "+v"(o[5]), "+v"(o[6]), "+v"(o[7]));
}

__device__ __forceinline__ void gload16(const void* g, void* l) {
  __builtin_amdgcn_global_load_lds((__attribute__((address_space(1))) void*)(g),
                                   (__attribute__((address_space(3))) void*)(l),
                                   16, 0, 0);
}

__device__ __forceinline__ void bar_v0() {
  asm volatile("s_waitcnt vmcnt(0)\n\ts_barrier" ::: "memory");
}
__device__ __forceinline__ void bar_v3() {
  asm volatile("s_waitcnt vmcnt(3)\n\ts_barrier" ::: "memory");
}

// ---------------- merged prep: all fp32->bf16 casts + rope table (verified) ----
__global__ __launch_bounds__(256)
void k_prep(const float* __restrict__ x, const float* __restrict__ wq,
            const float* __restrict__ wk, const float* __restrict__ wv,
            const float* __restrict__ wo, u16* __restrict__ xb,
            u16* __restrict__ wB, u16* __restrict__ wob,
            float* __restrict__ cost, float* __restrict__ sint) {
  const long i = (long)blockIdx.x * 256 + threadIdx.x;
  const float* src;
  u16* dst;
  long j;
  if (i < 6291456) {
    if (i < 2097152) { src = x; dst = xb; j = i; }
    else { src = wq; dst = wB; j = i - 2097152; }
  } else if (i < 8388608) {
    if (i < 7340032) { src = wk; dst = wB + 16777216; j = i - 6291456; }
    else { src = wv; dst = wB + 20971520; j = i - 7340032; }
  } else if (i < 12582912) {
    src = wo; dst = wob; j = i - 8388608;
  } else {
    long ti = i - 12582912;  // [0, 131072): rope table
    int s = (int)(ti >> 6), jj = (int)(ti & 63);
    float freq = powf(500000.0f, -(float)jj * (1.0f / 64.0f));
    float a = (float)s * freq;
    float sv, cv;
    sincosf(a, &sv, &cv);
    cost[ti] = cv;
    sint[ti] = sv;
    return;
  }
  f32x4 v = ((const f32x4_a*)src)[j];
  u16x4 o;
  o[0] = f2b(v[0]); o[1] = f2b(v[1]); o[2] = f2b(v[2]); o[3] = f2b(v[3]);
  ((u16x4_a*)dst)[j] = o;
}

// ================= 256^2 8-wave QKV GEMM (R11-verified, mid-loop B-stage) =========
#define QK_SCALE 0.08838834764831845f
__global__ __launch_bounds__(512, 2)
void k_gemm8(const u16* __restrict__ A, const u16* __restrict__ B,
             const float* __restrict__ cost, const float* __restrict__ sint,
             u16* __restrict__ Qb, u16* __restrict__ Kb, u16* __restrict__ Vt) {
  extern __shared__ u16 lds[];  // A: [2][256][64] @0, B: [2][256][64] @32768
  const int K = 4096;
  const int tid = threadIdx.x;
  const int w = tid >> 6, lane = tid & 63;
  const int hi = lane >> 4, lo = lane & 15;
  const int wr = w >> 2, wc = w & 3;  // 2M x 4N wave grid
  int bid = blockIdx.x;               // 192 = 8 XCD-groups x 24
  bid = (bid & 7) * 24 + (bid >> 3);
  const int tm = bid / 24, tn = bid - (bid / 24) * 24;
  const int m0 = tm << 8, n0 = tn << 8;

  const int kx = (((tid & 7) ^ ((tid >> 3) & 7)) << 3);  // elems
  const int r3 = tid >> 3;                               // 0..63

  f32x4 acc[8][4] = {};
  short8 afr[4][2], bfr[4][2];

  const int sA0 = (wr * 128 + lo) * 64;  // + fm*16*64
  const int sB0 = (wc * 64 + lo) * 64;   // + fn*16*64
  const int sl0 = ((0 * 4 + hi) ^ (lo & 7)) * 8;
  const int sl1 = ((1 * 4 + hi) ^ (lo & 7)) * 8;

#define STAGE_A(sbuf, h, kt)                                                    \
  {                                                                             \
    _Pragma("unroll") for (int l = 0; l < 2; ++l) {                             \
      gload16(A + (long)(m0 + (h)*128 + l * 64 + r3) * K + (kt)*64 + kx,        \
              lds + (sbuf)*16384 + ((h)*128 + l * 64 + w * 8) * 64);            \
    }                                                                           \
  }
#define STAGE_B(sbuf, h, kt)                                                    \
  {                                                                             \
    _Pragma("unroll") for (int l = 0; l < 2; ++l) {                             \
      gload16(B + (long)(n0 + (h)*128 + l * 64 + r3) * K + (kt)*64 + kx,        \
              lds + 32768 + (sbuf)*16384 + ((h)*128 + l * 64 + w * 8) * 64);    \
    }                                                                           \
  }

  // prologue: stage tile 0 -> buf0, drain once
  STAGE_A(0, 0, 0); STAGE_A(0, 1, 0);
  STAGE_B(0, 0, 0); STAGE_B(0, 1, 0);
  bar_v0();

  const int NI = K >> 7;  // 32 iters, 2 K-tiles each
#define HALF_ITER(buf, stile, sbuf, dostage)                                    \
  {                                                                             \
    const u16* Ab_ = lds + (buf)*16384;                                         \
    const u16* Bb_ = lds + 32768 + (buf)*16384;                                 \
    if (dostage) { STAGE_A(sbuf, 0, stile); STAGE_A(sbuf, 1, stile); }          \
    _Pragma("unroll") for (int fn = 0; fn < 4; ++fn) {                          \
      bfr[fn][0] = *(const short8_a*)(Bb_ + sB0 + fn * 1024 + sl0);             \
      bfr[fn][1] = *(const short8_a*)(Bb_ + sB0 + fn * 1024 + sl1);             \
    }                                                                           \
    _Pragma("unroll") for (int fm = 0; fm < 4; ++fm) {                          \
      afr[fm][0] = *(const short8_a*)(Ab_ + sA0 + fm * 1024 + sl0);             \
      afr[fm][1] = *(const short8_a*)(Ab_ + sA0 + fm * 1024 + sl1);             \
    }                                                                           \
    __builtin_amdgcn_s_setprio(1);                                              \
    _Pragma("unroll") for (int fm = 0; fm < 4; ++fm)                            \
      _Pragma("unroll") for (int fn = 0; fn < 4; ++fn) {                        \
        mfma_b(acc[fm][fn], afr[fm][0], bfr[fn][0]);                            \
        mfma_b(acc[fm][fn], afr[fm][1], bfr[fn][1]);                            \
      }                                                                         \
    __builtin_amdgcn_s_setprio(0);                                              \
    if (dostage) { STAGE_B(sbuf, 0, stile); STAGE_B(sbuf, 1, stile); }          \
    _Pragma("unroll") for (int fm = 0; fm < 4; ++fm) {                          \
      afr[fm][0] = *(const short8_a*)(Ab_ + sA0 + (fm + 4) * 1024 + sl0);       \
      afr[fm][1] = *(const short8_a*)(Ab_ + sA0 + (fm + 4) * 1024 + sl1);       \
    }                                                                           \
    __builtin_amdgcn_s_setprio(1);                                              \
    _Pragma("unroll") for (int fm = 0; fm < 4; ++fm)                            \
      _Pragma("unroll") for (int fn = 0; fn < 4; ++fn) {                        \
        mfma_b(acc[fm + 4][fn], afr[fm][0], bfr[fn][0]);                        \
        mfma_b(acc[fm + 4][fn], afr[fm][1], bfr[fn][1]);                        \
      }                                                                         \
    __builtin_amdgcn_s_setprio(0);                                              \
    bar_v0();                                                                   \
  }

  for (int it = 0; it < NI; ++it) {
    HALF_ITER(0, 2 * it + 1, 1, true);
    HALF_ITER(1, 2 * it + 2, 0, (it + 1 < NI));
  }

  guard8(&acc[0][0]); guard8(&acc[2][0]); guard8(&acc[4][0]); guard8(&acc[6][0]);

  if (n0 < 5120) {  // Q or K: RoPE (pair partner in lane lo^1)
    const bool isQ = (n0 < 4096);
#pragma unroll
    for (int fm = 0; fm < 8; ++fm) {
      const int row0 = m0 + wr * 128 + fm * 16 + hi * 4;
#pragma unroll
      for (int fn = 0; fn < 4; ++fn) {
        const int c = n0 + wc * 64 + fn * 16 + lo;
        const int j0 = (c & 127) >> 1;
        const bool even = ((c & 1) == 0);
#pragma unroll
        for (int r = 0; r < 4; ++r) {
          float own = acc[fm][fn][r];
          float part = __shfl_xor(own, 1);
          const int s_ = row0 + r;
          const float cv = cost[s_ * 64 + j0];
          const float sv = sint[s_ * 64 + j0];
          float res = even ? (own * cv - part * sv) : (part * sv + own * cv);
          if (isQ)
            Qb[(long)s_ * 4096 + c] = f2b(res * QK_SCALE);
          else
            Kb[(long)s_ * 1024 + (c - 4096)] = f2b(res);
        }
      }
    }
  } else {  // V: transposed store Vt[c][s], 4 rows packed
#pragma unroll
    for (int fm = 0; fm < 8; ++fm) {
      const int row0 = m0 + wr * 128 + fm * 16 + hi * 4;
#pragma unroll
      for (int fn = 0; fn < 4; ++fn) {
        const int vc = n0 - 5120 + wc * 64 + fn * 16 + lo;
        u16x4 pk;
#pragma unroll
        for (int r = 0; r < 4; ++r) pk[r] = f2b(acc[fm][fn][r]);
        *(u16x4_a*)(Vt + (long)vc * 2048 + row0) = pk;
      }
    }
  }
#undef HALF_ITER
#undef STAGE_A
#undef STAGE_B
}

// ---- 128x256-tile 8-wave out-projection (verified R11) ----
__global__ __launch_bounds__(512, 2)
void k_gemm_t2(const u16* __restrict__ A, const u16* __restrict__ B,
               float* __restrict__ C) {
  extern __shared__ u16 lds2[];
  u16* As = lds2;           // 3 bufs x 4096 elems (128 x 32)
  u16* Bs = lds2 + 12288;   // 3 bufs x 8192 elems (256 x 32)
  const int K = 4096, N = 4096;
  const int tid = threadIdx.x;
  const int w = tid >> 6, lane = tid & 63;
  const int hi = lane >> 4, lo = lane & 15;
  const int wr = w >> 2, wc = w & 3;
  int bid = blockIdx.x;               // 256 = 16(tm) x 16(tn)
  bid = (bid & 7) * 32 + (bid >> 3);  // XCD swizzle
  const int tm = bid >> 4, tn = bid & 15;
  const int m0 = tm << 7, n0 = tn << 8;

  const int r2 = tid >> 2;
  const int ks = (((tid & 3) ^ ((tid >> 3) & 3)) << 3);
  const u16* Ag = A + (long)(m0 + r2) * K + ks;
  const u16* Bg0 = B + (long)(n0 + r2) * K + ks;
  const u16* Bg1 = B + (long)(n0 + 128 + r2) * K + ks;
  const int sb = w * 512;

  f32x4 acc[4][4] = {};
  const int hs = hi ^ ((lo >> 1) & 3);
  const int aoff = (wr * 64 + lo) * 32 + hs * 8;
  const int boff = (wc * 64 + lo) * 32 + hs * 8;

  const int nt = K >> 5;
  int i0 = 0, i1 = 1, i2 = 2;

#define STG2(kt, bi)                                      \
  {                                                       \
    gload16(Ag + (kt)*32, As + (bi)*4096 + sb);           \
    gload16(Bg0 + (kt)*32, Bs + (bi)*8192 + sb);          \
    gload16(Bg1 + (kt)*32, Bs + (bi)*8192 + 4096 + sb);   \
  }

  STG2(0, 0);
  STG2(1, 1);
  bar_v3();

  for (int t = 0; t < nt; ++t) {
    if (t + 2 < nt) STG2(t + 2, i2);
    short8 af[4], bf[4];
#pragma unroll
    for (int m = 0; m < 4; ++m)
      af[m] = *(const short8_a*)(As + i0 * 4096 + aoff + m * 512);
#pragma unroll
    for (int n = 0; n < 4; ++n)
      bf[n] = *(const short8_a*)(Bs + i0 * 8192 + boff + n * 512);
    __builtin_amdgcn_s_setprio(1);
#pragma unroll
    for (int m = 0; m < 4; ++m)
#pragma unroll
      for (int n = 0; n < 4; ++n) mfma_b(acc[m][n], af[m], bf[n]);
    __builtin_amdgcn_s_setprio(0);
    if (t + 2 < nt) bar_v3();
    else bar_v0();
    const int tmp = i0; i0 = i1; i1 = i2; i2 = tmp;
  }
#undef STG2
  guard8(&acc[0][0]);
  guard8(&acc[2][0]);

#pragma unroll
  for (int m = 0; m < 4; ++m) {
    const int row0 = m0 + wr * 64 + m * 16 + hi * 4;
#pragma unroll
    for (int n = 0; n < 4; ++n) {
      const int col = n0 + wc * 64 + n * 16 + lo;
#pragma unroll
      for (int r = 0; r < 4; ++r)
        C[(long)(row0 + r) * N + col] = acc[m][n][r];
    }
  }
}

// -------- causal GQA flash attention (R13-verified, staged V) + T5 setprio --------
#define KLD 136
#define VLD 72
__global__ __launch_bounds__(256, 2)
void k_attn(const u16* __restrict__ Qb, const u16* __restrict__ Kb,
            const u16* __restrict__ Vt, u16* __restrict__ Ab) {
  __shared__ u16 Ks[64 * KLD];
  __shared__ u16 Vs[128 * VLD];
  __shared__ u16 Ps[4 * 16 * VLD];

  const int tid = threadIdx.x;
  const int w = tid >> 6, lane = tid & 63;
  const int hi = lane >> 4, lo = lane & 15;
  const int qt = 31 - (blockIdx.x >> 5);
  const int h = blockIdx.x & 31;
  const int hkv = h >> 2;
  const int q0 = qt * 64;
  const int qrow = q0 + w * 16 + lo;

  short8 qf[4];
#pragma unroll
  for (int c = 0; c < 4; ++c)
    qf[c] = *(const short8_a*)(Qb + (long)qrow * 4096 + h * 128 + c * 32 + hi * 8);

  f32x4 o[8] = {};
  float m_run = -1e30f, l_run = 0.f;
  u16* Pw = Ps + w * (16 * VLD);

  const int ntiles = qt + 1;
  for (int t = 0; t < ntiles; ++t) {
    const int kv0 = t * 64;
    __syncthreads();
#pragma unroll
    for (int r = 0; r < 4; ++r) {
      int i = r * 256 + tid;
      int key = i >> 4, d8 = (i & 15) * 8;
      short8 v = *(const short8_a*)(Kb + (long)(kv0 + key) * 1024 + hkv * 128 + d8);
      *(short8_a*)(Ks + key * KLD + d8) = v;
    }
#pragma unroll
    for (int r = 0; r < 4; ++r) {
      int i = r * 256 + tid;
      int dd = i >> 3, k8 = (i & 7) * 8;
      short8 v = *(const short8_a*)(Vt + (long)hkv * 262144 + (long)dd * 2048 + kv0 + k8);
      *(short8_a*)(Vs + dd * VLD + k8) = v;
    }
    __syncthreads();

    f32x4 sc[4] = {};
    __builtin_amdgcn_s_setprio(1);  // T5: favor this wave's QK^T MFMA cluster
#pragma unroll
    for (int c = 0; c < 4; ++c) {
#pragma unroll
      for (int kt = 0; kt < 4; ++kt) {
        short8 kf = *(const short8_a*)(Ks + (kt * 16 + lo) * KLD + c * 32 + hi * 8);
        mfma_b(sc[kt], kf, qf[c]);
      }
    }
    __builtin_amdgcn_s_setprio(0);
    guard4(sc[0], sc[1], sc[2], sc[3]);

    if (t == ntiles - 1) {
#pragma unroll
      for (int kt = 0; kt < 4; ++kt)
#pragma unroll
        for (int r = 0; r < 4; ++r) {
          int key = kv0 + kt * 16 + hi * 4 + r;
          if (key > qrow) sc[kt][r] = -1e30f;
        }
    }
    float tmax = -1e30f;
#pragma unroll
    for (int kt = 0; kt < 4; ++kt)
#pragma unroll
      for (int r = 0; r < 4; ++r) tmax = fmaxf(tmax, sc[kt][r]);
    tmax = fmaxf(tmax, __shfl_xor(tmax, 16));
    tmax = fmaxf(tmax, __shfl_xor(tmax, 32));
    float m_new = fmaxf(m_run, tmax);
    float scale = __expf(m_run - m_new);
    float psum = 0.f;
    float p[16];
#pragma unroll
    for (int kt = 0; kt < 4; ++kt)
#pragma unroll
      for (int r = 0; r < 4; ++r) {
        float pv = __expf(sc[kt][r] - m_new);
        p[kt * 4 + r] = pv;
        psum += pv;
      }
    psum += __shfl_xor(psum, 16);
    psum += __shfl_xor(psum, 32);
    l_run = l_run * scale + psum;
    m_run = m_new;
    float srow[4];
#pragma unroll
    for (int r = 0; r < 4; ++r) srow[r] = __shfl(scale, hi * 4 + r);
#pragma unroll
    for (int n = 0; n < 8; ++n)
#pragma unroll
      for (int r = 0; r < 4; ++r) o[n][r] *= srow[r];
#pragma unroll
    for (int kt = 0; kt < 4; ++kt) {
      unsigned p01 = (unsigned)f2b(p[kt * 4]) | ((unsigned)f2b(p[kt * 4 + 1]) << 16);
      unsigned p23 = (unsigned)f2b(p[kt * 4 + 2]) | ((unsigned)f2b(p[kt * 4 + 3]) << 16);
      *(uint_a*)(Pw + lo * VLD + kt * 16 + hi * 4) = p01;
      *(uint_a*)(Pw + lo * VLD + kt * 16 + hi * 4 + 2) = p23;
    }
    __syncthreads();
    __builtin_amdgcn_s_setprio(1);  // T5: favor PV MFMA cluster
#pragma unroll
    for (int c = 0; c < 2; ++c) {
      short8 pf = *(const short8_a*)(Pw + lo * VLD + c * 32 + hi * 8);
#pragma unroll
      for (int n = 0; n < 8; ++n) {
        short8 vf = *(const short8_a*)(Vs + (n * 16 + lo) * VLD + c * 32 + hi * 8);
        mfma_b(o[n], pf, vf);
      }
    }
    __builtin_amdgcn_s_setprio(0);
  }
  guard8(o);

  float inv = 1.0f / l_run;
  float irow[4];
#pragma unroll
  for (int r = 0; r < 4; ++r) irow[r] = __shfl(inv, hi * 4 + r);
#pragma unroll
  for (int n = 0; n < 8; ++n)
#pragma unroll
    for (int r = 0; r < 4; ++r) {
      int q = q0 + w * 16 + hi * 4 + r;
      Ab[(long)q * 4096 + h * 128 + n * 16 + lo] = f2b(o[n][r] * irow[r]);
    }
}

// ---------------- host ----------------
extern "C" void kernel_launch(void* const* d_in, const int* in_sizes, int n_in,
                              void* d_out, int out_size, void* d_ws, size_t ws_size,
                              hipStream_t stream) {
  const float* x = (const float*)d_in[0];
  const float* wq = (const float*)d_in[1];
  const float* wk = (const float*)d_in[2];
  const float* wv = (const float*)d_in[3];
  const float* wo = (const float*)d_in[4];
  float* out = (float*)d_out;
  char* ws = (char*)d_ws;

  size_t off = 0;
  u16* xb = (u16*)(ws + off); off += 16777216;     // x 2048x4096 bf16
  u16* wB = (u16*)(ws + off); off += 50331648;     // [wq;wk;wv] 6144x4096 bf16
  u16* wob = (u16*)(ws + off); off += 33554432;    // wo bf16
  u16* Qb = (u16*)(ws + off); off += 16777216;     // roped, scaled Q
  u16* Kb = (u16*)(ws + off); off += 4194304;      // roped K
  u16* Vtb = (u16*)(ws + off); off += 4194304;     // transposed V
  float* cost = (float*)(ws + off); off += 524288; // 2048x64
  float* sint = (float*)(ws + off); off += 524288;
  u16* Ab = (u16*)(ws + off); off += 16777216;     // attn out

  static bool attr_set = false;
  if (!attr_set) {
    hipFuncSetAttribute((const void*)k_gemm8,
                        hipFuncAttributeMaxDynamicSharedMemorySize, 131072);
    hipFuncSetAttribute((const void*)k_gemm_t2,
                        hipFuncAttributeMaxDynamicSharedMemorySize, 73728);
    attr_set = true;
  }

  // prep: all weight/x casts + rope table
  k_prep<<<49664, 256, 0, stream>>>(x, wq, wk, wv, wo, xb, wB, wob, cost, sint);

  // fused QKV projection (R11-verified k_gemm8, mid-loop B-stage)
  k_gemm8<<<192, 512, 131072, stream>>>(xb, wB, cost, sint, Qb, Kb, Vtb);

  // attention (R13-verified + T5 setprio on MFMA clusters)
  k_attn<<<1024, 256, 0, stream>>>(Qb, Kb, Vtb, Ab);

  // output projection (verified R11)
  k_gemm_t2<<<256, 512, 73728, stream>>>(Ab, wob, out);
}